// Round 3
// baseline (261.225 us; speedup 1.0000x reference)
//
#include <hip/hip_runtime.h>

// ws layout (float offsets)
#define OFF_PRE 0   // 65536*4 floats: pre[t*512+b][q] = x[b,t,:]@W_enc[:512] + b_enc

typedef float vf4 __attribute__((ext_vector_type(4)));

// ---- DPP rotate-reduce within each 16-lane row (full sum lands in all lanes)
template<int CTRL>
__device__ __forceinline__ float dpp_movf(float x) {
  return __int_as_float(__builtin_amdgcn_update_dpp(
      0, __float_as_int(x), CTRL, 0xf, 0xf, true));
}
__device__ __forceinline__ float rowsum16(float x) {
  x += dpp_movf<0x128>(x);   // row_ror:8
  x += dpp_movf<0x124>(x);   // row_ror:4
  x += dpp_movf<0x122>(x);   // row_ror:2
  x += dpp_movf<0x121>(x);   // row_ror:1
  return x;
}

__device__ __forceinline__ float fast_tanh(float x) {
  // tanh(x) = 1 - 2/(exp(2x)+1); exp via v_exp_f32 (exp2), rcp via v_rcp_f32
  float e = __builtin_amdgcn_exp2f(x * 2.8853902f);          // 2*log2(e)
  return 1.0f - 2.0f * __builtin_amdgcn_rcpf(e + 1.0f);
}

// ---------------------------------------------------------------------------
// pre[t,b,:] = x[b,t,:] @ W_enc[:512,:] + b_enc      (memory-bound, 128 MB read)
// 16 lanes per row; lane j covers e = c*64 + j*4 + {0..3}, c = 0..7
// x is read once and never reused -> nontemporal (keep pre resident in L2)
// ---------------------------------------------------------------------------
__global__ __launch_bounds__(256, 2) void enc_gemm(const float* __restrict__ x,
                                                   const float* __restrict__ W_enc,
                                                   const float* __restrict__ b_enc,
                                                   float* __restrict__ ws) {
  const int j = threadIdx.x & 15;
  const int g = (blockIdx.x * 256 + threadIdx.x) >> 4;     // group id: 0..8191

  float4 W[8][4];
  #pragma unroll
  for (int c = 0; c < 8; ++c)
    #pragma unroll
    for (int k = 0; k < 4; ++k)
      W[c][k] = *(const float4*)&W_enc[(c * 64 + j * 4 + k) * 4];

  const float4 be = *(const float4*)b_enc;
  float* pre = ws + OFF_PRE;

  for (int r = g; r < 65536; r += 8192) {                  // row = b*128 + t
    const vf4* xr = (const vf4*)(x + (size_t)r * 512);
    float a0 = 0.f, a1 = 0.f, a2 = 0.f, a3 = 0.f;
    #pragma unroll
    for (int c = 0; c < 8; ++c) {
      vf4 xv = __builtin_nontemporal_load(&xr[c * 16 + j]);
      a0 = fmaf(xv.x, W[c][0].x, a0); a0 = fmaf(xv.y, W[c][1].x, a0);
      a0 = fmaf(xv.z, W[c][2].x, a0); a0 = fmaf(xv.w, W[c][3].x, a0);
      a1 = fmaf(xv.x, W[c][0].y, a1); a1 = fmaf(xv.y, W[c][1].y, a1);
      a1 = fmaf(xv.z, W[c][2].y, a1); a1 = fmaf(xv.w, W[c][3].y, a1);
      a2 = fmaf(xv.x, W[c][0].z, a2); a2 = fmaf(xv.y, W[c][1].z, a2);
      a2 = fmaf(xv.z, W[c][2].z, a2); a2 = fmaf(xv.w, W[c][3].z, a2);
      a3 = fmaf(xv.x, W[c][0].w, a3); a3 = fmaf(xv.y, W[c][1].w, a3);
      a3 = fmaf(xv.z, W[c][2].w, a3); a3 = fmaf(xv.w, W[c][3].w, a3);
    }
    a0 = rowsum16(a0); a1 = rowsum16(a1); a2 = rowsum16(a2); a3 = rowsum16(a3);
    if (j == 0) {
      const int t = r & 127, b = r >> 7;
      *(float4*)&pre[(size_t)(t * 512 + b) * 4] =
          make_float4(a0 + be.x, a1 + be.y, a2 + be.z, a3 + be.w);
    }
  }
}

// ---------------------------------------------------------------------------
// Recurrence: 16 lanes per sample; lane = one statevector index.
// Prologue: each lane builds row sl of V in-register by simulating V^T e_sl
// (reversed circuit, transposed gates; CNOT is symmetric), plus its H row.
// Per step: ang = tanh(pre + h@W2); enc = product state; w = Vrow . enc;
// p = |w|^2; z_j = rowsum16(p*H[sl][j]) (DPP); h = tanh(z + br).
// Latency-bound: 128 serial steps, chain ~160 cy; pre loads prefetched 2 ahead.
// ---------------------------------------------------------------------------
__global__ __launch_bounds__(64) void recur_kernel(const float* __restrict__ theta,
                                                   const float* __restrict__ W_read,
                                                   const float* __restrict__ b_read,
                                                   const float* __restrict__ W_enc,
                                                   const float* __restrict__ ws,
                                                   float* __restrict__ out) {
  const int gtid = blockIdx.x * 64 + threadIdx.x;
  const int s  = gtid >> 4;               // sample 0..511
  const int sl = threadIdx.x & 15;        // statevector index

  // ---- per-lane constants ----
  float W2[16];
  #pragma unroll
  for (int jj = 0; jj < 16; ++jj) W2[jj] = W_enc[2048 + jj];   // rows 512..515 of (516,4)
  const float br0 = b_read[0], br1 = b_read[1], br2 = b_read[2], br3 = b_read[3];

  float Hv0 = 0.f, Hv1 = 0.f, Hv2 = 0.f, Hv3 = 0.f;
  #pragma unroll
  for (int q = 0; q < 4; ++q) {
    float sgn = ((sl >> (3 - q)) & 1) ? -1.0f : 1.0f;   // wire q <-> bit (3-q)
    Hv0 += sgn * W_read[q * 4 + 0];
    Hv1 += sgn * W_read[q * 4 + 1];
    Hv2 += sgn * W_read[q * 4 + 2];
    Hv3 += sgn * W_read[q * 4 + 3];
  }

  // ---- V row sl: simulate V^T e_sl = reversed circuit with transposed gates ----
  float Vr[16], Vi[16];
  #pragma unroll
  for (int i = 0; i < 16; ++i) { Vr[i] = (i == sl) ? 1.f : 0.f; Vi[i] = 0.f; }

  #pragma unroll
  for (int l = 1; l >= 0; --l) {
    #pragma unroll
    for (int c = 2; c >= 0; --c) {                         // CNOT(c,c+1), reversed order
      const int mc = 8 >> c, mt = 8 >> (c + 1);
      #pragma unroll
      for (int i = 0; i < 16; ++i) {
        if ((i & mc) && !(i & mt)) {
          const int i1 = i | mt;
          float tr = Vr[i]; Vr[i] = Vr[i1]; Vr[i1] = tr;
          float ti = Vi[i]; Vi[i] = Vi[i1]; Vi[i1] = ti;
        }
      }
    }
    #pragma unroll
    for (int q = 0; q < 4; ++q) {                          // 1q gates commute; transposed
      const float a0 = 0.5f * theta[l * 12 + q * 3 + 0];   // RX angle/2
      const float a1 = 0.5f * theta[l * 12 + q * 3 + 1];   // RZ angle/2
      const float a2 = 0.5f * theta[l * 12 + q * 3 + 2];   // RY angle/2
      float cx = cosf(a0), sx = sinf(a0);
      float cz = cosf(a1), sz = sinf(a1);
      float cy = cosf(a2), sy = sinf(a2);
      // M = RZ @ RX
      float m00r =  cz * cx, m00i = -sz * cx;
      float m01r = -sz * sx, m01i = -cz * sx;
      float m10r =  sz * sx, m10i = -cz * sx;
      float m11r =  cz * cx, m11i =  sz * cx;
      // U = RY @ M   (RY real)
      float u00r = cy * m00r - sy * m10r, u00i = cy * m00i - sy * m10i;
      float u01r = cy * m01r - sy * m11r, u01i = cy * m01i - sy * m11i;
      float u10r = sy * m00r + cy * m10r, u10i = sy * m00i + cy * m10i;
      float u11r = sy * m01r + cy * m11r, u11i = sy * m01i + cy * m11i;
      const int m = 8 >> q;                                // wire q <-> bit (3-q)
      #pragma unroll
      for (int i = 0; i < 16; ++i) {
        if (i & m) continue;
        const int i1 = i | m;
        float ar = Vr[i], ai = Vi[i], brr = Vr[i1], bii = Vi[i1];
        // transposed 2x2: [[u00,u10],[u01,u11]]
        Vr[i]  = u00r * ar - u00i * ai + u10r * brr - u10i * bii;
        Vi[i]  = u00r * ai + u00i * ar + u10r * bii + u10i * brr;
        Vr[i1] = u01r * ar - u01i * ai + u11r * brr - u11i * bii;
        Vi[i1] = u01r * ai + u01i * ar + u11r * bii + u11i * brr;
      }
    }
  }

  // ---- recurrence ----
  const float4* pre4 = (const float4*)(ws + OFF_PRE);
  float h0 = 0.f, h1 = 0.f, h2 = 0.f, h3 = 0.f;
  float4 pv0 = pre4[s];                   // t = 0
  float4 pv1 = pre4[512 + s];             // t = 1

  for (int t = 0; t < 128; ++t) {
    const int tn = (t + 2 < 128) ? t + 2 : 127;
    float4 pv2 = pre4[tn * 512 + s];      // prefetch distance 2

    // u_j = pv_j + sum_k h_k W2[j + 4k]   (2-level tree, depth ~12 cy)
    float u0 = fmaf(h0, W2[0],  fmaf(h1, W2[4],  pv0.x)) + fmaf(h2, W2[8],  h3 * W2[12]);
    float u1 = fmaf(h0, W2[1],  fmaf(h1, W2[5],  pv0.y)) + fmaf(h2, W2[9],  h3 * W2[13]);
    float u2 = fmaf(h0, W2[2],  fmaf(h1, W2[6],  pv0.z)) + fmaf(h2, W2[10], h3 * W2[14]);
    float u3 = fmaf(h0, W2[3],  fmaf(h1, W2[7],  pv0.w)) + fmaf(h2, W2[11], h3 * W2[15]);
    float t0 = fast_tanh(u0), t1 = fast_tanh(u1), t2 = fast_tanh(u2), t3 = fast_tanh(u3);
    // sin/cos(ang/2) = sin/cos(2*pi * tanh/4): HW sin/cos take revolutions
    float r0 = t0 * 0.25f, r1 = t1 * 0.25f, r2 = t2 * 0.25f, r3 = t3 * 0.25f;
    float c0 = __builtin_amdgcn_cosf(r0), s0 = __builtin_amdgcn_sinf(r0);
    float c1 = __builtin_amdgcn_cosf(r1), s1 = __builtin_amdgcn_sinf(r1);
    float c2 = __builtin_amdgcn_cosf(r2), s2 = __builtin_amdgcn_sinf(r2);
    float c3 = __builtin_amdgcn_cosf(r3), s3 = __builtin_amdgcn_sinf(r3);

    // product-state tree: enc[j], j = w0*8 + w1*4 + w2*2 + w3
    float e00 = c0 * c1, e01 = c0 * s1, e10 = s0 * c1, e11 = s0 * s1;
    float f0 = e00 * c2, f1 = e00 * s2, f2 = e01 * c2, f3 = e01 * s2;
    float f4 = e10 * c2, f5 = e10 * s2, f6 = e11 * c2, f7 = e11 * s2;
    float enc[16];
    enc[0]  = f0 * c3; enc[1]  = f0 * s3; enc[2]  = f1 * c3; enc[3]  = f1 * s3;
    enc[4]  = f2 * c3; enc[5]  = f2 * s3; enc[6]  = f3 * c3; enc[7]  = f3 * s3;
    enc[8]  = f4 * c3; enc[9]  = f4 * s3; enc[10] = f5 * c3; enc[11] = f5 * s3;
    enc[12] = f6 * c3; enc[13] = f6 * s3; enc[14] = f7 * c3; enc[15] = f7 * s3;

    // this lane's final amplitude: row sl of V times enc (enc real)
    // 4 independent 4-FMA chains + pairwise adds (depth ~24 cy)
    float wa = Vr[0] * enc[0], wb = Vr[4] * enc[4], wc = Vr[8] * enc[8], wd = Vr[12] * enc[12];
    float xa = Vi[0] * enc[0], xb = Vi[4] * enc[4], xc = Vi[8] * enc[8], xd = Vi[12] * enc[12];
    #pragma unroll
    for (int jj = 1; jj < 4; ++jj) {
      wa = fmaf(Vr[jj],      enc[jj],      wa); xa = fmaf(Vi[jj],      enc[jj],      xa);
      wb = fmaf(Vr[jj + 4],  enc[jj + 4],  wb); xb = fmaf(Vi[jj + 4],  enc[jj + 4],  xb);
      wc = fmaf(Vr[jj + 8],  enc[jj + 8],  wc); xc = fmaf(Vi[jj + 8],  enc[jj + 8],  xc);
      wd = fmaf(Vr[jj + 12], enc[jj + 12], wd); xd = fmaf(Vi[jj + 12], enc[jj + 12], xd);
    }
    float wr = (wa + wb) + (wc + wd);
    float wi = (xa + xb) + (xc + xd);
    float p  = fmaf(wr, wr, wi * wi);

    // z_j = sum over the 16 lanes of p * H[sl][j]  (DPP rotate-reduce, ~VALU cost)
    float z0 = rowsum16(p * Hv0);
    float z1 = rowsum16(p * Hv1);
    float z2 = rowsum16(p * Hv2);
    float z3 = rowsum16(p * Hv3);

    h0 = fast_tanh(z0 + br0);
    h1 = fast_tanh(z1 + br1);
    h2 = fast_tanh(z2 + br2);
    h3 = fast_tanh(z3 + br3);
    pv0 = pv1; pv1 = pv2;
  }
  if (sl == 0) *(float4*)&out[s * 4] = make_float4(h0, h1, h2, h3);
}

extern "C" void kernel_launch(void* const* d_in, const int* in_sizes, int n_in,
                              void* d_out, int out_size, void* d_ws, size_t ws_size,
                              hipStream_t stream) {
  const float* x      = (const float*)d_in[0];   // (512,128,512)
  const float* W_enc  = (const float*)d_in[1];   // (516,4)
  const float* b_enc  = (const float*)d_in[2];   // (4)
  const float* theta  = (const float*)d_in[3];   // (2,4,3)
  const float* W_read = (const float*)d_in[4];   // (4,4)
  const float* b_read = (const float*)d_in[5];   // (4)
  float* out = (float*)d_out;                    // (512,4)
  float* ws  = (float*)d_ws;

  hipLaunchKernelGGL(enc_gemm, dim3(512), dim3(256), 0, stream,
                     x, W_enc, b_enc, ws);
  hipLaunchKernelGGL(recur_kernel, dim3(128), dim3(64), 0, stream,
                     theta, W_read, b_read, W_enc, ws, out);
}

// Round 5
// 246.333 us; speedup vs baseline: 1.0605x; 1.0605x over previous
//
#include <hip/hip_runtime.h>

// ws layout (float offsets)
#define OFF_PRE 0   // 65536*4 floats: pre[t*512+b][q] = x[b,t,:]@W_enc[:512] + b_enc

// ---- DPP rotate-reduce within each 16-lane row (full sum lands in all lanes)
template<int CTRL>
__device__ __forceinline__ float dpp_movf(float x) {
  return __int_as_float(__builtin_amdgcn_update_dpp(
      0, __float_as_int(x), CTRL, 0xf, 0xf, true));
}
__device__ __forceinline__ float rowsum16(float x) {
  x += dpp_movf<0x128>(x);   // row_ror:8
  x += dpp_movf<0x124>(x);   // row_ror:4
  x += dpp_movf<0x122>(x);   // row_ror:2
  x += dpp_movf<0x121>(x);   // row_ror:1
  return x;
}

__device__ __forceinline__ float fast_tanh(float x) {
  // tanh(x) = 1 - 2/(exp(2x)+1); exp via v_exp_f32 (exp2), rcp via v_rcp_f32
  float e = __builtin_amdgcn_exp2f(x * 2.8853902f);          // 2*log2(e)
  return 1.0f - 2.0f * __builtin_amdgcn_rcpf(e + 1.0f);
}

// ---------------------------------------------------------------------------
// pre[t,b,:] = x[b,t,:] @ W_enc[:512,:] + b_enc      (memory-bound, 128 MB read)
// 16 lanes per row; lane j covers e = c*64 + j*4 + {0..3}, c = 0..7
// ---------------------------------------------------------------------------
__global__ __launch_bounds__(256, 2) void enc_gemm(const float* __restrict__ x,
                                                   const float* __restrict__ W_enc,
                                                   const float* __restrict__ b_enc,
                                                   float* __restrict__ ws) {
  const int j = threadIdx.x & 15;
  const int g = (blockIdx.x * 256 + threadIdx.x) >> 4;     // group id: 0..8191

  float4 W[8][4];
  #pragma unroll
  for (int c = 0; c < 8; ++c)
    #pragma unroll
    for (int k = 0; k < 4; ++k)
      W[c][k] = *(const float4*)&W_enc[(c * 64 + j * 4 + k) * 4];

  const float4 be = *(const float4*)b_enc;
  float* pre = ws + OFF_PRE;

  for (int r = g; r < 65536; r += 8192) {                  // row = b*128 + t
    const float* xr = x + (size_t)r * 512;
    float a0 = 0.f, a1 = 0.f, a2 = 0.f, a3 = 0.f;
    #pragma unroll
    for (int c = 0; c < 8; ++c) {
      float4 xv = *(const float4*)&xr[c * 64 + (j << 2)];
      a0 = fmaf(xv.x, W[c][0].x, a0); a0 = fmaf(xv.y, W[c][1].x, a0);
      a0 = fmaf(xv.z, W[c][2].x, a0); a0 = fmaf(xv.w, W[c][3].x, a0);
      a1 = fmaf(xv.x, W[c][0].y, a1); a1 = fmaf(xv.y, W[c][1].y, a1);
      a1 = fmaf(xv.z, W[c][2].y, a1); a1 = fmaf(xv.w, W[c][3].y, a1);
      a2 = fmaf(xv.x, W[c][0].z, a2); a2 = fmaf(xv.y, W[c][1].z, a2);
      a2 = fmaf(xv.z, W[c][2].z, a2); a2 = fmaf(xv.w, W[c][3].z, a2);
      a3 = fmaf(xv.x, W[c][0].w, a3); a3 = fmaf(xv.y, W[c][1].w, a3);
      a3 = fmaf(xv.z, W[c][2].w, a3); a3 = fmaf(xv.w, W[c][3].w, a3);
    }
    a0 = rowsum16(a0); a1 = rowsum16(a1); a2 = rowsum16(a2); a3 = rowsum16(a3);
    if (j == 0) {
      const int t = r & 127, b = r >> 7;
      *(float4*)&pre[(size_t)(t * 512 + b) * 4] =
          make_float4(a0 + be.x, a1 + be.y, a2 + be.z, a3 + be.w);
    }
  }
}

// ---------------------------------------------------------------------------
// Recurrence: 16 lanes per sample, 4 samples per 64-thread block.
// Stage this block's 8 KB of pre into LDS up front (latency overlapped with the
// in-register V-row prologue), then run 128 serial steps purely on LDS+VALU.
// Per step: ang = tanh(pre + h@W2); enc = product state; w = Vrow . enc;
// p = |w|^2; z_j = rowsum16(p*H[sl][j]) (DPP); h = tanh(z + br).
// ---------------------------------------------------------------------------
__global__ __launch_bounds__(64) void recur_kernel(const float* __restrict__ theta,
                                                   const float* __restrict__ W_read,
                                                   const float* __restrict__ b_read,
                                                   const float* __restrict__ W_enc,
                                                   const float* __restrict__ ws,
                                                   float* __restrict__ out) {
  __shared__ float4 lpre[128][4];         // [t][sample-in-block]
  const int tid = threadIdx.x;
  const int s_base = blockIdx.x * 4;
  const int grp = tid >> 4;               // sample-in-block 0..3
  const int s   = s_base + grp;           // global sample
  const int sl  = tid & 15;               // statevector index

  // ---- issue LDS staging loads first (latency hides under the V prologue) ----
  const float4* pre4 = (const float4*)(ws + OFF_PRE);
  {
    const int tt = tid >> 2, j4 = tid & 3;
    #pragma unroll
    for (int k = 0; k < 8; ++k) {
      const int t = k * 16 + tt;
      lpre[t][j4] = pre4[(size_t)t * 512 + s_base + j4];
    }
  }

  // ---- per-lane constants ----
  float W2[16];
  #pragma unroll
  for (int jj = 0; jj < 16; ++jj) W2[jj] = W_enc[2048 + jj];   // rows 512..515 of (516,4)
  const float br0 = b_read[0], br1 = b_read[1], br2 = b_read[2], br3 = b_read[3];

  float Hv0 = 0.f, Hv1 = 0.f, Hv2 = 0.f, Hv3 = 0.f;
  #pragma unroll
  for (int q = 0; q < 4; ++q) {
    float sgn = ((sl >> (3 - q)) & 1) ? -1.0f : 1.0f;   // wire q <-> bit (3-q)
    Hv0 += sgn * W_read[q * 4 + 0];
    Hv1 += sgn * W_read[q * 4 + 1];
    Hv2 += sgn * W_read[q * 4 + 2];
    Hv3 += sgn * W_read[q * 4 + 3];
  }

  // ---- V row sl: simulate V^T e_sl = reversed circuit with transposed gates ----
  float Vr[16], Vi[16];
  #pragma unroll
  for (int i = 0; i < 16; ++i) { Vr[i] = (i == sl) ? 1.f : 0.f; Vi[i] = 0.f; }

  #pragma unroll
  for (int l = 1; l >= 0; --l) {
    #pragma unroll
    for (int c = 2; c >= 0; --c) {                         // CNOT(c,c+1), reversed order
      const int mc = 8 >> c, mt = 8 >> (c + 1);
      #pragma unroll
      for (int i = 0; i < 16; ++i) {
        if ((i & mc) && !(i & mt)) {
          const int i1 = i | mt;
          float tr = Vr[i]; Vr[i] = Vr[i1]; Vr[i1] = tr;
          float ti = Vi[i]; Vi[i] = Vi[i1]; Vi[i1] = ti;
        }
      }
    }
    #pragma unroll
    for (int q = 0; q < 4; ++q) {                          // 1q gates commute; transposed
      const float a0 = 0.5f * theta[l * 12 + q * 3 + 0];   // RX angle/2
      const float a1 = 0.5f * theta[l * 12 + q * 3 + 1];   // RZ angle/2
      const float a2 = 0.5f * theta[l * 12 + q * 3 + 2];   // RY angle/2
      float cx = cosf(a0), sx = sinf(a0);
      float cz = cosf(a1), sz = sinf(a1);
      float cy = cosf(a2), sy = sinf(a2);
      // M = RZ @ RX
      float m00r =  cz * cx, m00i = -sz * cx;
      float m01r = -sz * sx, m01i = -cz * sx;
      float m10r =  sz * sx, m10i = -cz * sx;
      float m11r =  cz * cx, m11i =  sz * cx;
      // U = RY @ M   (RY real)
      float u00r = cy * m00r - sy * m10r, u00i = cy * m00i - sy * m10i;
      float u01r = cy * m01r - sy * m11r, u01i = cy * m01i - sy * m11i;
      float u10r = sy * m00r + cy * m10r, u10i = sy * m00i + cy * m10i;
      float u11r = sy * m01r + cy * m11r, u11i = sy * m01i + cy * m11i;
      const int m = 8 >> q;                                // wire q <-> bit (3-q)
      #pragma unroll
      for (int i = 0; i < 16; ++i) {
        if (i & m) continue;
        const int i1 = i | m;
        float ar = Vr[i], ai = Vi[i], brr = Vr[i1], bii = Vi[i1];
        // transposed 2x2: [[u00,u10],[u01,u11]]
        Vr[i]  = u00r * ar - u00i * ai + u10r * brr - u10i * bii;
        Vi[i]  = u00r * ai + u00i * ar + u10r * bii + u10i * brr;
        Vr[i1] = u01r * ar - u01i * ai + u11r * brr - u11i * bii;
        Vi[i1] = u01r * ai + u01i * ar + u11r * bii + u11i * brr;
      }
    }
  }

  __syncthreads();                         // staging complete

  // ---- recurrence (pure LDS + VALU; LDS reads prefetched 2 ahead) ----
  float h0 = 0.f, h1 = 0.f, h2 = 0.f, h3 = 0.f;
  float4 pv0 = lpre[0][grp];
  float4 pv1 = lpre[1][grp];

  for (int t = 0; t < 128; ++t) {
    const int tn = (t + 2 < 128) ? t + 2 : 127;
    float4 pv2 = lpre[tn][grp];            // broadcast read, no bank conflict

    // u_j = pv_j + sum_k h_k W2[j + 4k]   (2-level tree)
    float u0 = fmaf(h0, W2[0],  fmaf(h1, W2[4],  pv0.x)) + fmaf(h2, W2[8],  h3 * W2[12]);
    float u1 = fmaf(h0, W2[1],  fmaf(h1, W2[5],  pv0.y)) + fmaf(h2, W2[9],  h3 * W2[13]);
    float u2 = fmaf(h0, W2[2],  fmaf(h1, W2[6],  pv0.z)) + fmaf(h2, W2[10], h3 * W2[14]);
    float u3 = fmaf(h0, W2[3],  fmaf(h1, W2[7],  pv0.w)) + fmaf(h2, W2[11], h3 * W2[15]);
    float t0 = fast_tanh(u0), t1 = fast_tanh(u1), t2 = fast_tanh(u2), t3 = fast_tanh(u3);
    // sin/cos(ang/2) = sin/cos(2*pi * tanh/4): HW sin/cos take revolutions
    float r0 = t0 * 0.25f, r1 = t1 * 0.25f, r2 = t2 * 0.25f, r3 = t3 * 0.25f;
    float c0 = __builtin_amdgcn_cosf(r0), s0 = __builtin_amdgcn_sinf(r0);
    float c1 = __builtin_amdgcn_cosf(r1), s1 = __builtin_amdgcn_sinf(r1);
    float c2 = __builtin_amdgcn_cosf(r2), s2 = __builtin_amdgcn_sinf(r2);
    float c3 = __builtin_amdgcn_cosf(r3), s3 = __builtin_amdgcn_sinf(r3);

    // product-state tree: enc[j], j = w0*8 + w1*4 + w2*2 + w3
    float e00 = c0 * c1, e01 = c0 * s1, e10 = s0 * c1, e11 = s0 * s1;
    float f0 = e00 * c2, f1 = e00 * s2, f2 = e01 * c2, f3 = e01 * s2;
    float f4 = e10 * c2, f5 = e10 * s2, f6 = e11 * c2, f7 = e11 * s2;
    float enc[16];
    enc[0]  = f0 * c3; enc[1]  = f0 * s3; enc[2]  = f1 * c3; enc[3]  = f1 * s3;
    enc[4]  = f2 * c3; enc[5]  = f2 * s3; enc[6]  = f3 * c3; enc[7]  = f3 * s3;
    enc[8]  = f4 * c3; enc[9]  = f4 * s3; enc[10] = f5 * c3; enc[11] = f5 * s3;
    enc[12] = f6 * c3; enc[13] = f6 * s3; enc[14] = f7 * c3; enc[15] = f7 * s3;

    // this lane's final amplitude: row sl of V times enc (enc real)
    // 4 independent 4-FMA chains + pairwise adds
    float wa = Vr[0] * enc[0], wb = Vr[4] * enc[4], wc = Vr[8] * enc[8], wd = Vr[12] * enc[12];
    float xa = Vi[0] * enc[0], xb = Vi[4] * enc[4], xc = Vi[8] * enc[8], xd = Vi[12] * enc[12];
    #pragma unroll
    for (int jj = 1; jj < 4; ++jj) {
      wa = fmaf(Vr[jj],      enc[jj],      wa); xa = fmaf(Vi[jj],      enc[jj],      xa);
      wb = fmaf(Vr[jj + 4],  enc[jj + 4],  wb); xb = fmaf(Vi[jj + 4],  enc[jj + 4],  xb);
      wc = fmaf(Vr[jj + 8],  enc[jj + 8],  wc); xc = fmaf(Vi[jj + 8],  enc[jj + 8],  xc);
      wd = fmaf(Vr[jj + 12], enc[jj + 12], wd); xd = fmaf(Vi[jj + 12], enc[jj + 12], xd);
    }
    float wr = (wa + wb) + (wc + wd);
    float wi = (xa + xb) + (xc + xd);
    float p  = fmaf(wr, wr, wi * wi);

    // z_j = sum over the 16 lanes of p * H[sl][j]  (DPP rotate-reduce)
    float z0 = rowsum16(p * Hv0);
    float z1 = rowsum16(p * Hv1);
    float z2 = rowsum16(p * Hv2);
    float z3 = rowsum16(p * Hv3);

    h0 = fast_tanh(z0 + br0);
    h1 = fast_tanh(z1 + br1);
    h2 = fast_tanh(z2 + br2);
    h3 = fast_tanh(z3 + br3);
    pv0 = pv1; pv1 = pv2;
  }
  if (sl == 0) *(float4*)&out[s * 4] = make_float4(h0, h1, h2, h3);
}

extern "C" void kernel_launch(void* const* d_in, const int* in_sizes, int n_in,
                              void* d_out, int out_size, void* d_ws, size_t ws_size,
                              hipStream_t stream) {
  const float* x      = (const float*)d_in[0];   // (512,128,512)
  const float* W_enc  = (const float*)d_in[1];   // (516,4)
  const float* b_enc  = (const float*)d_in[2];   // (4)
  const float* theta  = (const float*)d_in[3];   // (2,4,3)
  const float* W_read = (const float*)d_in[4];   // (4,4)
  const float* b_read = (const float*)d_in[5];   // (4)
  float* out = (float*)d_out;                    // (512,4)
  float* ws  = (float*)d_ws;

  hipLaunchKernelGGL(enc_gemm, dim3(512), dim3(256), 0, stream,
                     x, W_enc, b_enc, ws);
  hipLaunchKernelGGL(recur_kernel, dim3(128), dim3(64), 0, stream,
                     theta, W_read, b_read, W_enc, ws, out);
}